// Round 13
// baseline (95.731 us; speedup 1.0000x reference)
//
#include <hip/hip_runtime.h>

#define NN 100000
#define NE 1600000
#define DIN 128
#define DOUT 32
#define NBUK 391     // ceil(NN/256) buckets of 256 nodes
#define FILLB 512    // edge chunks (512*3125 = NE exactly)
#define CHUNK 3125   // edges per chunk
#define CAP 8192     // max records per bucket staged in LDS (mean 4092, sd ~64)
#define NTILES 6250  // NN/16 MFMA row-tiles
#define XWB 782      // ceil(6250 / 8 waves)

typedef unsigned short ushort_t;
typedef unsigned int uint_t;
typedef _Float16 f16x8 __attribute__((ext_vector_type(8)));
typedef float f32x4 __attribute__((ext_vector_type(4)));

static __device__ __forceinline__ ushort_t f2h_u(float f) {
    _Float16 h = (_Float16)f;
    ushort_t u;
    __builtin_memcpy(&u, &h, 2);
    return u;
}
static __device__ __forceinline__ float h2f(ushort_t us) {
    _Float16 h;
    __builtin_memcpy(&h, &us, 2);
    return (float)h;
}

// ===========================================================================
// k0: blocks 0..7: Wht[c][k] = f16(W[k][c]); block 8: zero bsum.
// ===========================================================================
__global__ __launch_bounds__(512)
void wb_zero_kernel(const float* __restrict__ W, ushort_t* __restrict__ Wht,
                    int* __restrict__ bsum) {
    if (blockIdx.x < 8) {
        int i = blockIdx.x * 512 + threadIdx.x;   // 0..4095
        int c = i >> 7, k = i & 127;
        Wht[(size_t)c * DIN + k] = f2h_u(W[(size_t)k * DOUT + c]);
    } else {
        int t = threadIdx.x;
        if (t < NBUK) bsum[t] = 0;
    }
}

// ===========================================================================
// k1: FUSED fill + xw.
// Blocks [0, FILLB): per-chunk LDS counting sort of records by bucket, then
//   a fully COALESCED write of the chunk to records[blk*CHUNK..] (6.4 MB
//   exact, no scattered global writes). Chunk-local offsets -> histmat,
//   bucket totals -> bsum (int atomics).
// Blocks [FILLB, FILLB+XWB): xwsh[r] = f16(x[r] @ W) via MFMA (unscaled; dis
//   scaling happens in sort's epilogue). 8 waves * 16 rows per block.
// record = (row << 8) | (col & 255)
// ===========================================================================
__global__ __launch_bounds__(512)
void fill_xw_kernel(const int* __restrict__ row, const int* __restrict__ col,
                    int* __restrict__ histmat, int* __restrict__ bsum,
                    unsigned int* __restrict__ records,
                    const float* __restrict__ x, const ushort_t* __restrict__ Wht,
                    ushort_t* __restrict__ xwsh) {
    __shared__ unsigned int stage[CHUNK];   // 12.5 KB
    __shared__ int hist[NBUK];
    __shared__ int s[512];
    __shared__ int lcur[NBUK];
    if (blockIdx.x < FILLB) {
        int t = threadIdx.x, blk = blockIdx.x;
        for (int bb = t; bb < NBUK; bb += 512) hist[bb] = 0;
        __syncthreads();
        int e0 = blk * CHUNK;
        for (int j = t; j < CHUNK; j += 512) atomicAdd(&hist[col[e0 + j] >> 8], 1);
        __syncthreads();
        int own = (t < NBUK) ? hist[t] : 0;
        s[t] = own;
        __syncthreads();
        for (int off = 1; off < 512; off <<= 1) {
            int u = (t >= off) ? s[t - off] : 0;
            __syncthreads();
            s[t] += u;
            __syncthreads();
        }
        int excl = s[t] - own;                 // t==NBUK -> 3125 (own=0)
        if (t <= NBUK) histmat[(size_t)blk * (NBUK + 1) + t] = excl;
        if (t < NBUK) {
            if (own) atomicAdd(&bsum[t], own);
            lcur[t] = excl;
        }
        __syncthreads();
        // scatter into LDS stage (grouped by bucket within the chunk)
        for (int j = t; j < CHUNK; j += 512) {
            int e = e0 + j;
            int c = col[e];
            int slot = atomicAdd(&lcur[c >> 8], 1);
            stage[slot] = ((unsigned int)row[e] << 8) | (unsigned int)(c & 255);
        }
        __syncthreads();
        // coalesced write-out of the whole chunk
        for (int j = t; j < CHUNK; j += 512)
            records[(size_t)blk * CHUNK + j] = stage[j];
        return;
    }
    // ---- xw part: 8 waves x 16 rows ----
    int t = threadIdx.x;
    int wv = t >> 6, lane = t & 63;
    int wtile = (blockIdx.x - FILLB) * 8 + wv;
    if (wtile >= NTILES) return;           // uniform per wave
    int r0 = wtile * 16;
    int rowi = lane & 15;                  // A-row / B-col / D-col
    int kg = lane >> 4;                    // k-group (0..3)

    f16x8 bfrag[2][4];
#pragma unroll
    for (int t2 = 0; t2 < 2; ++t2)
#pragma unroll
        for (int ss = 0; ss < 4; ++ss)
            bfrag[t2][ss] = *(const f16x8*)(Wht + (size_t)(t2 * 16 + rowi) * DIN + ss * 32 + kg * 8);

    const float* __restrict__ xr = x + (size_t)(r0 + rowi) * DIN;
    float4 xa[8];
#pragma unroll
    for (int ss = 0; ss < 4; ++ss) {
        xa[2 * ss]     = *(const float4*)(xr + ss * 32 + kg * 8);
        xa[2 * ss + 1] = *(const float4*)(xr + ss * 32 + kg * 8 + 4);
    }
    f16x8 afrag[4];
#pragma unroll
    for (int ss = 0; ss < 4; ++ss) {
        f16x8 a;
        a[0] = (_Float16)xa[2 * ss].x;     a[1] = (_Float16)xa[2 * ss].y;
        a[2] = (_Float16)xa[2 * ss].z;     a[3] = (_Float16)xa[2 * ss].w;
        a[4] = (_Float16)xa[2 * ss + 1].x; a[5] = (_Float16)xa[2 * ss + 1].y;
        a[6] = (_Float16)xa[2 * ss + 1].z; a[7] = (_Float16)xa[2 * ss + 1].w;
        afrag[ss] = a;
    }

    f32x4 acc0 = {0.f, 0.f, 0.f, 0.f};
    f32x4 acc1 = {0.f, 0.f, 0.f, 0.f};
#pragma unroll
    for (int ss = 0; ss < 4; ++ss) {
        acc0 = __builtin_amdgcn_mfma_f32_16x16x32_f16(afrag[ss], bfrag[0][ss], acc0, 0, 0, 0);
        acc1 = __builtin_amdgcn_mfma_f32_16x16x32_f16(afrag[ss], bfrag[1][ss], acc1, 0, 0, 0);
    }

#pragma unroll
    for (int j = 0; j < 4; ++j) {
        int orow = r0 + kg * 4 + j;
        xwsh[(size_t)orow * DOUT + rowi]      = f2h_u(acc0[j]);
        xwsh[(size_t)orow * DOUT + 16 + rowi] = f2h_u(acc1[j]);
    }
}

// ===========================================================================
// k2: exclusive scan of bucket totals -> base[NBUK+1]
// ===========================================================================
__global__ __launch_bounds__(512)
void bscan_kernel(const int* __restrict__ bsum, int* __restrict__ base) {
    __shared__ int s[512];
    int t = threadIdx.x;
    int own = (t < NBUK) ? bsum[t] : 0;
    s[t] = own;
    __syncthreads();
    for (int off = 1; off < 512; off <<= 1) {
        int v = (t >= off) ? s[t - off] : 0;
        __syncthreads();
        s[t] += v;
        __syncthreads();
    }
    if (t < NBUK) {
        base[t] = s[t] - own;
        if (t == NBUK - 1) base[NBUK] = s[t];
    }
}

// ===========================================================================
// k3: per-bucket: gather this bucket's segments from the 512 chunk regions
// (scattered READS, L2/L3-absorbed), group by node (LDS counting sort),
// write srcs (contiguous region), compute dis/offs, scale xwsh by dis.
// ===========================================================================
__global__ __launch_bounds__(512)
void sort_kernel(const int* __restrict__ base, const int* __restrict__ histmat,
                 const unsigned int* __restrict__ records,
                 int* __restrict__ srcs, float* __restrict__ dis,
                 int* __restrict__ offs, ushort_t* __restrict__ xwsh) {
    __shared__ unsigned int stage[CAP];  // 32 KB
    __shared__ int slen[512];
    __shared__ int hist[256];
    __shared__ int sc[256];
    __shared__ int lcur[256];
    __shared__ float disL[256];
    int b = blockIdx.x, t = threadIdx.x;
    // segment of chunk t belonging to bucket b
    int s_off = histmat[(size_t)t * (NBUK + 1) + b];
    int e_off = histmat[(size_t)t * (NBUK + 1) + b + 1];
    int len = e_off - s_off;
    slen[t] = len;
    __syncthreads();
    for (int off = 1; off < 512; off <<= 1) {
        int u = (t >= off) ? slen[t - off] : 0;
        __syncthreads();
        slen[t] += u;
        __syncthreads();
    }
    int pos = slen[t] - len;
    int cnt = slen[511];
    const unsigned int* seg = records + (size_t)t * CHUNK + s_off;
    for (int k = 0; k < len; ++k) stage[pos + k] = seg[k];
    if (t < 256) hist[t] = 0;
    __syncthreads();
    for (int j = t; j < cnt; j += 512) atomicAdd(&hist[stage[j] & 255u], 1);
    __syncthreads();
    int d = (t < 256) ? hist[t] : 0;
    if (t < 256) sc[t] = d;
    __syncthreads();
    for (int off = 1; off < 256; off <<= 1) {
        int u = (t < 256 && t >= off) ? sc[t - off] : 0;
        __syncthreads();
        if (t < 256) sc[t] += u;
        __syncthreads();
    }
    int sbase = base[b];
    if (t < 256) {
        int excl = sc[t] - d;
        float dv = rsqrtf((float)(d + 1));
        disL[t] = dv;
        int n = (b << 8) + t;
        if (n < NN) {
            dis[n] = dv;
            offs[n] = sbase + excl;
            if (n == NN - 1) offs[NN] = sbase + cnt;
        }
        lcur[t] = excl;
    }
    __syncthreads();
    for (int j = t; j < cnt; j += 512) {
        unsigned int rec = stage[j];
        int slot = atomicAdd(&lcur[rec & 255u], 1);
        srcs[sbase + slot] = (int)(rec >> 8);
    }
    // epilogue: scale this bucket's xwsh rows by dis (coalesced u32 r/w)
    int n0 = b << 8;
    for (int idx = t; idx < 256 * 16; idx += 512) {   // 16 u32 per row
        int loc = idx >> 4;
        int n = n0 + loc;
        if (n >= NN) break;
        uint_t* p = (uint_t*)(xwsh + ((size_t)n << 5)) + (idx & 15);
        uint_t v = *p;
        float dv = disL[loc];
        float lo = h2f((ushort_t)(v & 0xffffu)) * dv;
        float hi = h2f((ushort_t)(v >> 16)) * dv;
        *p = (uint_t)f2h_u(lo) | ((uint_t)f2h_u(hi) << 16);
    }
}

// ===========================================================================
// k4: aggregate, zero-reduce layout. Half-wave (32 lanes) = one node; lane
// owns one output dim and serially walks the node's edge list. Per edge the
// 32 lanes read one coalesced 64B row (u16/lane); f32 accumulate; unroll 8.
// ===========================================================================
__global__ __launch_bounds__(256)
void aggregate_kernel(const int* __restrict__ offs, const int* __restrict__ srcs,
                      const float* __restrict__ dis, const ushort_t* __restrict__ xwsh,
                      const float* __restrict__ bias, float* __restrict__ out) {
    int gw = (int)((blockIdx.x * (long long)blockDim.x + threadIdx.x) >> 6);
    int half = (threadIdx.x >> 5) & 1;
    int wid = gw * 2 + half;
    if (wid >= NN) return;
    int d = threadIdx.x & 31;

    int s = offs[wid], e = offs[wid + 1];
    float acc = h2f(xwsh[((size_t)wid << 5) + d]);   // self-loop
    int i = s;
    for (; i + 8 <= e; i += 8) {
        int r0 = srcs[i + 0], r1 = srcs[i + 1], r2 = srcs[i + 2], r3 = srcs[i + 3];
        int r4 = srcs[i + 4], r5 = srcs[i + 5], r6 = srcs[i + 6], r7 = srcs[i + 7];
        ushort_t u0 = xwsh[((size_t)r0 << 5) + d];
        ushort_t u1 = xwsh[((size_t)r1 << 5) + d];
        ushort_t u2 = xwsh[((size_t)r2 << 5) + d];
        ushort_t u3 = xwsh[((size_t)r3 << 5) + d];
        ushort_t u4 = xwsh[((size_t)r4 << 5) + d];
        ushort_t u5 = xwsh[((size_t)r5 << 5) + d];
        ushort_t u6 = xwsh[((size_t)r6 << 5) + d];
        ushort_t u7 = xwsh[((size_t)r7 << 5) + d];
        acc += h2f(u0); acc += h2f(u1); acc += h2f(u2); acc += h2f(u3);
        acc += h2f(u4); acc += h2f(u5); acc += h2f(u6); acc += h2f(u7);
    }
    if (i + 4 <= e) {
        int r0 = srcs[i + 0], r1 = srcs[i + 1], r2 = srcs[i + 2], r3 = srcs[i + 3];
        ushort_t u0 = xwsh[((size_t)r0 << 5) + d];
        ushort_t u1 = xwsh[((size_t)r1 << 5) + d];
        ushort_t u2 = xwsh[((size_t)r2 << 5) + d];
        ushort_t u3 = xwsh[((size_t)r3 << 5) + d];
        acc += h2f(u0); acc += h2f(u1); acc += h2f(u2); acc += h2f(u3);
        i += 4;
    }
    for (; i < e; ++i) acc += h2f(xwsh[((size_t)srcs[i] << 5) + d]);

    out[((size_t)wid << 5) + d] = dis[wid] * acc + bias[d];
}

// ===========================================================================
// Fallback path (R1) if workspace is too small
// ===========================================================================
__global__ void deg_count_kernel(const int* __restrict__ col, int* __restrict__ deg) {
    int e = blockIdx.x * blockDim.x + threadIdx.x;
    if (e < NE) atomicAdd(&deg[col[e]], 1);
}
__global__ void dis_kernel(const int* __restrict__ deg, float* __restrict__ dis) {
    int i = blockIdx.x * blockDim.x + threadIdx.x;
    if (i < NN) dis[i] = rsqrtf((float)(deg[i] + 1));
}
__global__ void xw_init_kernel(const float* __restrict__ x, const float* __restrict__ W,
                               const float* __restrict__ b, const float* __restrict__ dis,
                               float* __restrict__ xw, float* __restrict__ out) {
    __shared__ float Ws[DIN * DOUT];
    for (int i = threadIdx.x; i < DIN * DOUT; i += blockDim.x) Ws[i] = W[i];
    __syncthreads();
    int idx = blockIdx.x * blockDim.x + threadIdx.x;
    if (idx >= NN * DOUT) return;
    int n = idx >> 5;
    int d = idx & (DOUT - 1);
    const float* xr = x + (long long)n * DIN;
    float acc = 0.f;
#pragma unroll
    for (int k = 0; k < DIN; ++k) acc += xr[k] * Ws[k * DOUT + d];
    xw[idx] = acc;
    float di = dis[n];
    out[idx] = di * di * acc + b[d];
}
__global__ void scatter_kernel(const int* __restrict__ row, const int* __restrict__ col,
                               const float* __restrict__ dis, const float* __restrict__ xw,
                               float* __restrict__ out) {
    long long idx = (long long)blockIdx.x * blockDim.x + threadIdx.x;
    if (idx >= (long long)NE * DOUT) return;
    int e = (int)(idx >> 5);
    int d = (int)(idx & (DOUT - 1));
    int r = row[e];
    int c = col[e];
    atomicAdd(&out[c * DOUT + d], dis[r] * dis[c] * xw[r * DOUT + d]);
}

// ===========================================================================
extern "C" void kernel_launch(void* const* d_in, const int* in_sizes, int n_in,
                              void* d_out, int out_size, void* d_ws, size_t ws_size,
                              hipStream_t stream) {
    const float* x  = (const float*)d_in[0];
    const int*   ei = (const int*)d_in[1];
    const float* W  = (const float*)d_in[2];
    const float* b  = (const float*)d_in[3];
    float* out = (float*)d_out;

    const int* row = ei;       // edge_index[0] = source
    const int* col = ei + NE;  // edge_index[1] = target

    char* ws = (char*)d_ws;
    int*          histmat = (int*)(ws + 0);          //   802,816 B (512*392*4)
    int*          bsum    = (int*)(ws + 802816);     //     1,564 B
    int*          base    = (int*)(ws + 804480);     //     1,568 B (NBUK+1)
    int*          offs    = (int*)(ws + 806144);     //   400,004 B (NN+1)
    float*        dis     = (float*)(ws + 1206272);  //   400,000 B
    unsigned int* records = (unsigned int*)(ws + 1606272);  // 6,400,000 B
    int*          srcs    = (int*)(ws + 8006272);    // 6,400,000 B
    ushort_t*     xwsh    = (ushort_t*)(ws + 14406272);     // 6,400,000 B
    ushort_t*     Wht     = (ushort_t*)(ws + 20806272);     //     8,192 B
    const size_t WS_NEEDED = 20814464ull;

    if (ws_size >= WS_NEEDED) {
        wb_zero_kernel<<<9, 512, 0, stream>>>(W, Wht, bsum);
        fill_xw_kernel<<<FILLB + XWB, 512, 0, stream>>>(row, col, histmat, bsum,
                                                        records, x, Wht, xwsh);
        bscan_kernel<<<1, 512, 0, stream>>>(bsum, base);
        sort_kernel<<<NBUK, 512, 0, stream>>>(base, histmat, records, srcs, dis, offs, xwsh);
        {
            long long waves = (NN + 1) / 2;             // 2 nodes per wave
            int bl = (int)((waves + 3) / 4);            // 4 waves per block
            aggregate_kernel<<<bl, 256, 0, stream>>>(offs, srcs, dis, xwsh, b, out);
        }
    } else {
        // fallback: atomic scatter path
        int* deg = (int*)(ws + 0);
        float* dis2 = (float*)(ws + 400128);
        float* xw = (float*)(ws + 800256);
        hipMemsetAsync(deg, 0, NN * sizeof(int), stream);
        {
            int th = 256, bl = (NE + th - 1) / th;
            deg_count_kernel<<<bl, th, 0, stream>>>(col, deg);
        }
        {
            int th = 256, bl = (NN + th - 1) / th;
            dis_kernel<<<bl, th, 0, stream>>>(deg, dis2);
        }
        {
            long long total = (long long)NN * DOUT;
            int bl = (int)((total + 255) / 256);
            xw_init_kernel<<<bl, 256, 0, stream>>>(x, W, b, dis2, xw, out);
        }
        {
            long long total = (long long)NE * DOUT;
            int bl = (int)((total + 255) / 256);
            scatter_kernel<<<bl, 256, 0, stream>>>(row, col, dis2, xw, out);
        }
    }
}